// Round 10
// baseline (487.710 us; speedup 1.0000x reference)
//
#include <hip/hip_runtime.h>
#include <math.h>

// Problem constants (from reference)
#define Bn    256
#define Tn    1024
#define In    64
#define Pn    256
#define En    128
#define NOUTn 64
#define LN_EPS 1e-5f

// softmax factorization constants (TEMP=8):
// z_j ∝ exp((j-2)*frac/4) * exp(-(j-2)^2/8)  (common exp(-frac^2/8) cancels)
#define C1f 0.3606737602222409f     // log2(e)/4
#define K1f 0.8824969025845955f     // exp(-1/8)
#define K2f 0.6065306597126334f     // exp(-4/8)

typedef float f32x2 __attribute__((ext_vector_type(2)));

__device__ __forceinline__ float tanh_fast(float x) {
    float e = __builtin_amdgcn_exp2f(x * 2.88539008177793f);   // e^(2x)
    return 1.0f - 2.0f * __builtin_amdgcn_rcpf(e + 1.0f);
}
__device__ __forceinline__ f32x2 tanh2(f32x2 x) {
    f32x2 e;
    e[0] = __builtin_amdgcn_exp2f(x[0] * 2.88539008177793f);
    e[1] = __builtin_amdgcn_exp2f(x[1] * 2.88539008177793f);
    f32x2 r;
    r[0] = __builtin_amdgcn_rcpf(e[0] + 1.0f);
    r[1] = __builtin_amdgcn_rcpf(e[1] + 1.0f);
    return 1.0f - 2.0f * r;
}

template<int CTRL, int RMASK>
__device__ __forceinline__ float dpp_add(float x) {
    return x + __int_as_float(__builtin_amdgcn_update_dpp(
        0, __float_as_int(x), CTRL, RMASK, 0xF, false));
}
__device__ __forceinline__ void wave_sum64_x3(float& x, float& y, float& z) {
#define LVL(C, R) x = dpp_add<C, R>(x); y = dpp_add<C, R>(y); z = dpp_add<C, R>(z);
    LVL(0x111, 0xF)
    LVL(0x112, 0xF)
    LVL(0x114, 0xF)
    LVL(0x118, 0xF)
    LVL(0x142, 0xA)
    LVL(0x143, 0xC)
#undef LVL
    x = __int_as_float(__builtin_amdgcn_readlane(__float_as_int(x), 63));
    y = __int_as_float(__builtin_amdgcn_readlane(__float_as_int(y), 63));
    z = __int_as_float(__builtin_amdgcn_readlane(__float_as_int(z), 63));
}

// ===========================================================================
// FULLY-FUSED kernel, zero workspace: 256 blocks x 192 threads (3 waves).
//   wave0 (consumer): scan step over 64 chunks of 16 timesteps; emb from a
//                     triple-buffered LDS stage. NEW vs R9: the JUMP
//                     candidate's 5-row window is VALUE-prefetched at the end
//                     of each step (after the scatter -> bit-exact), so jump
//                     steps no longer stall on ds_read latency; only the
//                     weight recompute (2 exp2 + rcp) stays on the chain.
//   waves1-2 (producers): emb chunk k+2 into stage buf[(k+2)%3] while the
//                     consumer scans chunk k (unchanged from R9).
// LDS: ring 128 KB + jd 1 KB + stage 3x8 KB = 153 KB.
// ===========================================================================
#define STAGE_FLOATS (3 * 16 * En)                 // 6144
#define LDSF_FLOATS  (Pn * En + Pn + STAGE_FLOATS) // 39168
#define LDSF_BYTES   (LDSF_FLOATS * 4)             // 156672

__global__ __launch_bounds__(192, 1)
void fused3_kernel(const float* __restrict__ x,
                   const float* __restrict__ pointer_init,
                   const float* __restrict__ W_in, const float* __restrict__ b_in,
                   const float* __restrict__ ln_w, const float* __restrict__ ln_b,
                   const float* __restrict__ jump_dest,
                   const float* __restrict__ Wg,  const float* __restrict__ bg,
                   const float* __restrict__ cs_ptr,
                   const float* __restrict__ Wo,  const float* __restrict__ bo,
                   float* __restrict__ out) {
    extern __shared__ float lds[];
    float* mem = lds;                    // ring: [row][2*l + c]
    float* jd  = lds + Pn * En;          // jump_dest copy
    float* stg = lds + Pn * En + Pn;     // stage: [buf3][tq4][e128][t4]

    const int b   = blockIdx.x;
    const int tid = threadIdx.x;

    if (tid >= 64) {
        // ================= PRODUCERS (waves 1,2): 4t x 4e register tile ======
        const int p    = tid - 64;        // 0..127
        const int tq   = p >> 5;          // 0..3 : which 4-t group of the chunk
        const int eidx = p & 31;          // e = eidx + 32*j, j=0..3
        float be[4];
        #pragma unroll
        for (int j = 0; j < 4; ++j) be[j] = b_in[eidx + 32 * j];
        const float* xb = x + (size_t)b * Tn * In;

#define PRODUCE(K, BUF) {                                                     \
    const int t0 = (K) * 16 + tq * 4;                                         \
    const float4* xr = (const float4*)(xb + t0 * In);   /* per-lane addr */   \
    float acc[4][4];                                                          \
    _Pragma("unroll")                                                         \
    for (int tt = 0; tt < 4; ++tt)                                            \
        _Pragma("unroll")                                                     \
        for (int j = 0; j < 4; ++j) acc[tt][j] = 0.f;                         \
    _Pragma("unroll")                                                         \
    for (int i4 = 0; i4 < 16; ++i4) {                                         \
        float4 xv[4];                                                         \
        _Pragma("unroll")                                                     \
        for (int tt = 0; tt < 4; ++tt) xv[tt] = xr[tt * 16 + i4];             \
        float4 wf[4];                                                         \
        _Pragma("unroll")                                                     \
        for (int j = 0; j < 4; ++j)                                           \
            wf[j] = *(const float4*)(W_in + (eidx + 32 * j) * In + i4 * 4);   \
        _Pragma("unroll")                                                     \
        for (int tt = 0; tt < 4; ++tt)                                        \
            _Pragma("unroll")                                                 \
            for (int j = 0; j < 4; ++j) {                                     \
                acc[tt][j] += xv[tt].x * wf[j].x;                             \
                acc[tt][j] += xv[tt].y * wf[j].y;                             \
                acc[tt][j] += xv[tt].z * wf[j].z;                             \
                acc[tt][j] += xv[tt].w * wf[j].w;                             \
            }                                                                 \
    }                                                                         \
    float* sg = stg + (BUF) * 2048 + tq * 512;                                \
    _Pragma("unroll")                                                         \
    for (int j = 0; j < 4; ++j) {                                             \
        float4 o;                                                             \
        o.x = tanh_fast(acc[0][j] + be[j]);                                   \
        o.y = tanh_fast(acc[1][j] + be[j]);                                   \
        o.z = tanh_fast(acc[2][j] + be[j]);                                   \
        o.w = tanh_fast(acc[3][j] + be[j]);                                   \
        *(float4*)(sg + (eidx + 32 * j) * 4) = o;                             \
    }                                                                         \
}
        PRODUCE(0, 0)
        PRODUCE(1, 1)
        __syncthreads();                   // #1: chunks 0,1 staged
        int buf = 2;
        for (int k = 0; k < 64; ++k) {
            if (k + 2 < 64) {
                PRODUCE(k + 2, buf)
                buf = (buf == 2) ? 0 : buf + 1;
            }
            __syncthreads();               // chunk boundary
        }
#undef PRODUCE
        __syncthreads();                   // final: hid broadcast
        return;
    }

    // ================= CONSUMER (wave 0) =====================================
    const int l = tid;

    float4* m4 = (float4*)mem;
    for (int i = l; i < Pn * En / 4; i += 64) m4[i] = make_float4(0.f, 0.f, 0.f, 0.f);
    for (int i = l; i < Pn; i += 64) jd[i] = jump_dest[i];

    const f32x2 lnw = {ln_w[l], ln_w[l + 64]};
    const f32x2 lnb = {ln_b[l], ln_b[l + 64]};
    const f32x2 wg  = {Wg[l],   Wg[l + 64]};
    const float bgs = bg[0];
    const float cs  = 1.0f / (1.0f + expf(-cs_ptr[0]));
    f32x2 hid = {0.f, 0.f};

    // ---- canonical (walk-assumed) state: dummy; forced jump at t=0 ----
    float ptr = 0.f; int base = 0;
    float z0 = 0.f, z1 = 0.f, z3 = 0.f, z4 = 0.f, inv = 1.f;   // z2 == 1
    f32x2 nb0 = {0,0}, nb1 = {0,0}, nb2 = {0,0}, nb3 = {0,0}, nb4 = {0,0};

    // ---- jump candidate for step 0: "jump" to pointer_init; window = zeros
    float jl      = 1.0f;
    float jmp_ptr = pointer_init[b];
    int   jmp_base = (int)jmp_ptr; jmp_base = jmp_base > 255 ? 255 : jmp_base;
    f32x2 J0 = {0,0}, J1 = {0,0}, J2 = {0,0}, J3 = {0,0}, J4 = {0,0};
    // (ring zeroed above, so a real gather would read exactly zero)

    __syncthreads();                       // #1: emb chunks 0,1 staged

    // A = current 4-step group registers (group tb=0)
    const float* sa0 = stg + 4 * l;        // buf0, group 0, ch l
    float4 A0 = *(const float4*)sa0;
    float4 A1 = *(const float4*)(sa0 + 256);

#define SSTEP(EC0, EC1) {                                                      \
    if (__builtin_amdgcn_readfirstlane(__float_as_int(jl)) > 0) {              \
        /* JUMP: values already prefetched; only weights on-chain */           \
        ptr  = jmp_ptr; base = jmp_base;                                       \
        nb0 = J0; nb1 = J1; nb2 = J2; nb3 = J3; nb4 = J4;                      \
        const float frac = ptr - (float)base;                                  \
        const float r  = __builtin_amdgcn_exp2f(frac * C1f);                   \
        const float ri = __builtin_amdgcn_exp2f(-frac * C1f);                  \
        z0 = K2f * ri * ri; z1 = K1f * ri;                                     \
        z3 = K1f * r;       z4 = K2f * r * r;                                  \
        inv = __builtin_amdgcn_rcpf(((z0 + z1) + (1.0f + z3)) + z4);           \
    }                                                                          \
    const float jt_nxt = jd[base];        /* issued early, used post-scatter */\
    float* r0 = mem + (((base + 254) & 255) << 7) + 2 * l;                     \
    float* r1 = mem + (((base + 255) & 255) << 7) + 2 * l;                     \
    float* r2 = mem + ((base) << 7) + 2 * l;                                   \
    float* r3 = mem + (((base + 1) & 255) << 7) + 2 * l;                       \
    float* r4 = mem + (((base + 2) & 255) << 7) + 2 * l;                       \
    const f32x2 ctx = inv * (((nb0 * z0 + nb1 * z1) + (nb2 + nb3 * z3))        \
                             + nb4 * z4);                                      \
    f32x2 em; em[0] = (EC0); em[1] = (EC1);                                    \
    const f32x2 su = tanh2(em + cs * ctx + hid);                               \
    const f32x2 g  = su * inv;                                                 \
    const f32x2 m0v = nb0 + z0 * g, m1v = nb1 + z1 * g, m2v = nb2 + g,         \
                m3v = nb3 + z3 * g, m4v = nb4 + z4 * g;                        \
    *(f32x2*)r0 = m0v; *(f32x2*)r1 = m1v; *(f32x2*)r2 = m2v;                   \
    *(f32x2*)r3 = m3v; *(f32x2*)r4 = m4v;                                      \
    /* walk staging for t+1 (zero-copy fall-through; z carried) */             \
    nb0 = m1v; nb1 = m2v; nb2 = m3v; nb3 = m4v;                                \
    nb4 = *(f32x2*)(mem + (((base + 3) & 255) << 7) + 2 * l);                  \
    ptr = ptr + 1.0f; if (ptr >= 256.0f) ptr -= 256.0f;                        \
    base = (base + 1) & 255;                                                   \
    /* jump-candidate VALUE prefetch for t+1 (post-scatter -> bit-exact) */    \
    jmp_ptr = jt_nxt;                                                          \
    int bj = (int)jt_nxt; bj = bj > 255 ? 255 : bj;                            \
    jmp_base = bj;                                                             \
    J0 = *(f32x2*)(mem + (((bj + 254) & 255) << 7) + 2 * l);                   \
    J1 = *(f32x2*)(mem + (((bj + 255) & 255) << 7) + 2 * l);                   \
    J2 = *(f32x2*)(mem + ((bj) << 7) + 2 * l);                                 \
    J3 = *(f32x2*)(mem + (((bj + 1) & 255) << 7) + 2 * l);                     \
    J4 = *(f32x2*)(mem + (((bj + 2) & 255) << 7) + 2 * l);                     \
    /* reductions + LN + gate */                                               \
    float s1 = su[0] + su[1];                                                  \
    const f32x2 sq = su * su;  float s2 = sq[0] + sq[1];                       \
    const f32x2 sg = su * wg;  float s3 = sg[0] + sg[1];                       \
    wave_sum64_x3(s1, s2, s3);                                                 \
    const float mu   = s1 * (1.0f / En);                                       \
    const float var  = s2 * (1.0f / En) - mu * mu;                             \
    const float rstd = __builtin_amdgcn_rsqf(var + LN_EPS);                    \
    hid = (su - mu) * rstd * lnw + lnb;                                        \
    jl  = s3 + bgs;                                                            \
}

    for (int k = 0; k < 64; ++k) {
        #pragma unroll
        for (int g2 = 0; g2 < 4; ++g2) {
            const int tb  = k * 4 + g2;
            int tbn = tb + 1; if (tbn > 255) tbn = 255;
            // prefetch next group: buf[(tbn>>2)%3] is never producer-active
            const float* sb = stg + ((tbn >> 2) % 3) * 2048 + (tbn & 3) * 512 + 4 * l;
            float4 B0 = *(const float4*)sb;
            float4 B1 = *(const float4*)(sb + 256);
            SSTEP(A0.x, A1.x)
            SSTEP(A0.y, A1.y)
            SSTEP(A0.z, A1.z)
            SSTEP(A0.w, A1.w)
            A0 = B0; A1 = B1;
        }
        __syncthreads();               // chunk boundary (chunk k+2 staged)
    }
#undef SSTEP

    // epilogue: logits = hid @ Wo^T + bo
    mem[l] = hid[0]; mem[64 + l] = hid[1];
    __syncthreads();                   // final
    const float4* w4 = (const float4*)(Wo + l * En);
    const float4* h4 = (const float4*)mem;
    float a0 = 0.f, a1 = 0.f, a2 = 0.f, a3 = 0.f;
    #pragma unroll
    for (int i = 0; i < En / 4; ++i) {
        float4 wv = w4[i]; float4 hv = h4[i];
        a0 += wv.x * hv.x; a1 += wv.y * hv.y; a2 += wv.z * hv.z; a3 += wv.w * hv.w;
    }
    out[b * NOUTn + l] = (a0 + a1) + (a2 + a3) + bo[l];
}

extern "C" void kernel_launch(void* const* d_in, const int* in_sizes, int n_in,
                              void* d_out, int out_size, void* d_ws, size_t ws_size,
                              hipStream_t stream) {
    const float* x            = (const float*)d_in[0];
    const float* pointer_init = (const float*)d_in[1];
    const float* W_in         = (const float*)d_in[2];
    const float* b_in         = (const float*)d_in[3];
    const float* ln_w         = (const float*)d_in[4];
    const float* ln_b         = (const float*)d_in[5];
    const float* jump_dest    = (const float*)d_in[6];
    const float* Wg           = (const float*)d_in[7];
    const float* bg           = (const float*)d_in[8];
    const float* cs           = (const float*)d_in[9];
    const float* Wo           = (const float*)d_in[10];
    const float* bo           = (const float*)d_in[11];
    float* out = (float*)d_out;
    (void)d_ws; (void)ws_size;   // no workspace needed: emb staged in LDS

    (void)hipFuncSetAttribute((const void*)fused3_kernel,
                              hipFuncAttributeMaxDynamicSharedMemorySize, LDSF_BYTES);
    fused3_kernel<<<Bn, 192, LDSF_BYTES, stream>>>(
        x, pointer_init, W_in, b_in, ln_w, ln_b, jump_dest, Wg, bg, cs,
        Wo, bo, out);
}

// Round 11
// 475.038 us; speedup vs baseline: 1.0267x; 1.0267x over previous
//
#include <hip/hip_runtime.h>
#include <math.h>

// Problem constants (from reference)
#define Bn    256
#define Tn    1024
#define In    64
#define Pn    256
#define En    128
#define NOUTn 64
#define LN_EPS 1e-5f

// softmax factorization constants (TEMP=8):
// z_j ∝ exp((j-2)*frac/4) * exp(-(j-2)^2/8)  (common exp(-frac^2/8) cancels)
#define C1f 0.3606737602222409f     // log2(e)/4
#define K1f 0.8824969025845955f     // exp(-1/8)
#define K2f 0.6065306597126334f     // exp(-4/8)

typedef float f32x2 __attribute__((ext_vector_type(2)));

__device__ __forceinline__ float tanh_fast(float x) {
    float e = __builtin_amdgcn_exp2f(x * 2.88539008177793f);   // e^(2x)
    return 1.0f - 2.0f * __builtin_amdgcn_rcpf(e + 1.0f);
}
__device__ __forceinline__ f32x2 tanh2(f32x2 x) {
    f32x2 e;
    e[0] = __builtin_amdgcn_exp2f(x[0] * 2.88539008177793f);
    e[1] = __builtin_amdgcn_exp2f(x[1] * 2.88539008177793f);
    f32x2 r;
    r[0] = __builtin_amdgcn_rcpf(e[0] + 1.0f);
    r[1] = __builtin_amdgcn_rcpf(e[1] + 1.0f);
    return 1.0f - 2.0f * r;
}

template<int CTRL, int RMASK>
__device__ __forceinline__ float dpp_add(float x) {
    return x + __int_as_float(__builtin_amdgcn_update_dpp(
        0, __float_as_int(x), CTRL, RMASK, 0xF, false));
}
__device__ __forceinline__ void wave_sum64_x3(float& x, float& y, float& z) {
#define LVL(C, R) x = dpp_add<C, R>(x); y = dpp_add<C, R>(y); z = dpp_add<C, R>(z);
    LVL(0x111, 0xF)
    LVL(0x112, 0xF)
    LVL(0x114, 0xF)
    LVL(0x118, 0xF)
    LVL(0x142, 0xA)
    LVL(0x143, 0xC)
#undef LVL
    x = __int_as_float(__builtin_amdgcn_readlane(__float_as_int(x), 63));
    y = __int_as_float(__builtin_amdgcn_readlane(__float_as_int(y), 63));
    z = __int_as_float(__builtin_amdgcn_readlane(__float_as_int(z), 63));
}

// ===========================================================================
// FULLY-FUSED kernel (R9 structure, best measured), zero workspace:
// 256 blocks x 192 threads (3 waves), one block per batch.
//   wave0 (consumer): scan4-style step over 64 chunks of 16 timesteps; emb
//                     read from a triple-buffered LDS stage (one b128 pair
//                     per 4-step group, prefetched one group ahead).
//   waves1-2 (producers): emb chunk k+2 into stage buf[(k+2)%3] while the
//                     consumer scans chunk k from buf[k%3]. Thread tile
//                     4t x 4e; x/W_in per-lane VMEM dwordx4.
// Triple buffering: during chunk k producers touch only buf[(k+2)%3];
// consumer reads buf[k%3] and prefetches at most into buf[(k+1)%3].
// LDS: ring 128 KB + jd 1 KB + stage 3x8 KB = 153 KB. Zero emb HBM traffic.
// R11 cleanup vs R9: rotating stage-buffer indices instead of per-group %3.
// ===========================================================================
#define STAGE_FLOATS (3 * 16 * En)                 // 6144
#define LDSF_FLOATS  (Pn * En + Pn + STAGE_FLOATS) // 39168
#define LDSF_BYTES   (LDSF_FLOATS * 4)             // 156672

__global__ __launch_bounds__(192, 1)
void fused2_kernel(const float* __restrict__ x,
                   const float* __restrict__ pointer_init,
                   const float* __restrict__ W_in, const float* __restrict__ b_in,
                   const float* __restrict__ ln_w, const float* __restrict__ ln_b,
                   const float* __restrict__ jump_dest,
                   const float* __restrict__ Wg,  const float* __restrict__ bg,
                   const float* __restrict__ cs_ptr,
                   const float* __restrict__ Wo,  const float* __restrict__ bo,
                   float* __restrict__ out) {
    extern __shared__ float lds[];
    float* mem = lds;                    // ring: [row][2*l + c]
    float* jd  = lds + Pn * En;          // jump_dest copy
    float* stg = lds + Pn * En + Pn;     // stage: [buf3][tq4][e128][t4]

    const int b   = blockIdx.x;
    const int tid = threadIdx.x;

    if (tid >= 64) {
        // ================= PRODUCERS (waves 1,2): 4t x 4e register tile ======
        const int p    = tid - 64;        // 0..127
        const int tq   = p >> 5;          // 0..3 : which 4-t group of the chunk
        const int eidx = p & 31;          // e = eidx + 32*j, j=0..3
        float be[4];
        #pragma unroll
        for (int j = 0; j < 4; ++j) be[j] = b_in[eidx + 32 * j];
        const float* xb = x + (size_t)b * Tn * In;

#define PRODUCE(K, BUF) {                                                     \
    const int t0 = (K) * 16 + tq * 4;                                         \
    const float4* xr = (const float4*)(xb + t0 * In);   /* per-lane addr */   \
    float acc[4][4];                                                          \
    _Pragma("unroll")                                                         \
    for (int tt = 0; tt < 4; ++tt)                                            \
        _Pragma("unroll")                                                     \
        for (int j = 0; j < 4; ++j) acc[tt][j] = 0.f;                         \
    _Pragma("unroll")                                                         \
    for (int i4 = 0; i4 < 16; ++i4) {                                         \
        float4 xv[4];                                                         \
        _Pragma("unroll")                                                     \
        for (int tt = 0; tt < 4; ++tt) xv[tt] = xr[tt * 16 + i4];             \
        float4 wf[4];                                                         \
        _Pragma("unroll")                                                     \
        for (int j = 0; j < 4; ++j)                                           \
            wf[j] = *(const float4*)(W_in + (eidx + 32 * j) * In + i4 * 4);   \
        _Pragma("unroll")                                                     \
        for (int tt = 0; tt < 4; ++tt)                                        \
            _Pragma("unroll")                                                 \
            for (int j = 0; j < 4; ++j) {                                     \
                acc[tt][j] += xv[tt].x * wf[j].x;                             \
                acc[tt][j] += xv[tt].y * wf[j].y;                             \
                acc[tt][j] += xv[tt].z * wf[j].z;                             \
                acc[tt][j] += xv[tt].w * wf[j].w;                             \
            }                                                                 \
    }                                                                         \
    float* sg = stg + (BUF) * 2048 + tq * 512;                                \
    _Pragma("unroll")                                                         \
    for (int j = 0; j < 4; ++j) {                                             \
        float4 o;                                                             \
        o.x = tanh_fast(acc[0][j] + be[j]);                                   \
        o.y = tanh_fast(acc[1][j] + be[j]);                                   \
        o.z = tanh_fast(acc[2][j] + be[j]);                                   \
        o.w = tanh_fast(acc[3][j] + be[j]);                                   \
        *(float4*)(sg + (eidx + 32 * j) * 4) = o;                             \
    }                                                                         \
}
        PRODUCE(0, 0)
        PRODUCE(1, 1)
        __syncthreads();                   // #1: chunks 0,1 staged
        int buf = 2;
        for (int k = 0; k < 64; ++k) {
            if (k + 2 < 64) {
                PRODUCE(k + 2, buf)
                buf = (buf == 2) ? 0 : buf + 1;
            }
            __syncthreads();               // chunk boundary
        }
#undef PRODUCE
        __syncthreads();                   // final: hid broadcast
        return;
    }

    // ================= CONSUMER (wave 0): scan4 step, LDS-staged emb =========
    const int l = tid;

    float4* m4 = (float4*)mem;
    for (int i = l; i < Pn * En / 4; i += 64) m4[i] = make_float4(0.f, 0.f, 0.f, 0.f);
    for (int i = l; i < Pn; i += 64) jd[i] = jump_dest[i];

    const f32x2 lnw = {ln_w[l], ln_w[l + 64]};
    const f32x2 lnb = {ln_b[l], ln_b[l + 64]};
    const f32x2 wg  = {Wg[l],   Wg[l + 64]};
    const float bgs = bg[0];
    const float cs  = 1.0f / (1.0f + expf(-cs_ptr[0]));
    f32x2 hid = {0.f, 0.f};

    float* myb = mem + 2 * l;

    // ---- pipeline state (scan4: forced jump to pointer_init at t=0) ----
    float jl      = 1.0f;
    float jt_cur  = pointer_init[b];
    float ptrW    = 0.f;
    int   baseW   = 0;
    float jtW_pre = 0.f;
    float z0 = 0.f, z1 = 0.f, z2 = 1.f, z3 = 0.f, z4 = 0.f, inv = 1.f;
    f32x2 wnb0 = {0,0}, wnb1 = {0,0}, wnb2 = {0,0}, wnb3 = {0,0}, wnb4 = {0,0};
    float *wp0 = myb, *wp1 = myb, *wp2 = myb, *wp3 = myb, *wp4 = myb;

    __syncthreads();                       // #1: emb chunks 0,1 staged

    // A = current 4-step group registers (group tb=0, buf 0)
    const float* sa0 = stg + 4 * l;
    float4 A0 = *(const float4*)sa0;
    float4 A1 = *(const float4*)(sa0 + 256);

#define SSTEP(EC0, EC1) {                                                      \
    float ptr; int base;                                                       \
    f32x2 nb0, nb1, nb2, nb3, nb4;                                             \
    float *p0, *p1, *p2, *p3, *p4;                                             \
    float jt_nxt;                                                              \
    if (__builtin_amdgcn_readfirstlane(__float_as_int(jl)) > 0) {              \
        /* JUMP: full gather + weight recompute */                             \
        ptr  = jt_cur;                                                         \
        base = (int)ptr; base = base > 255 ? 255 : base;                       \
        p0 = mem + (((base + 254) & 255) << 7) + 2 * l;                        \
        p1 = mem + (((base + 255) & 255) << 7) + 2 * l;                        \
        p2 = mem + (base << 7) + 2 * l;                                        \
        p3 = mem + (((base + 1) & 255) << 7) + 2 * l;                          \
        p4 = mem + (((base + 2) & 255) << 7) + 2 * l;                          \
        nb0 = *(f32x2*)p0; nb1 = *(f32x2*)p1; nb2 = *(f32x2*)p2;               \
        nb3 = *(f32x2*)p3; nb4 = *(f32x2*)p4;                                  \
        jt_nxt = jd[base];                                                     \
        const float frac = ptr - (float)base;                                  \
        const float r  = __builtin_amdgcn_exp2f(frac * C1f);                   \
        const float ri = __builtin_amdgcn_exp2f(-frac * C1f);                  \
        z0 = K2f * ri * ri; z1 = K1f * ri; z2 = 1.0f;                          \
        z3 = K1f * r;       z4 = K2f * r * r;                                  \
        inv = __builtin_amdgcn_rcpf(((z0 + z1) + (z2 + z3)) + z4);             \
    } else {                                                                   \
        /* WALK: weights carried, window = scattered regs + prefetched row */  \
        ptr = ptrW; base = baseW;                                              \
        nb0 = wnb0; nb1 = wnb1; nb2 = wnb2; nb3 = wnb3; nb4 = wnb4;            \
        p0 = wp0; p1 = wp1; p2 = wp2; p3 = wp3; p4 = wp4;                      \
        jt_nxt = jtW_pre;                                                      \
    }                                                                          \
    const f32x2 ctx = inv * (((nb0 * z0 + nb1 * z1) + (nb2 * z2 + nb3 * z3))   \
                             + nb4 * z4);                                      \
    f32x2 em; em[0] = (EC0); em[1] = (EC1);                                    \
    const f32x2 su = tanh2(em + cs * ctx + hid);                               \
    const f32x2 g  = su * inv;                                                 \
    const f32x2 m0v = nb0 + z0 * g, m1v = nb1 + z1 * g, m2v = nb2 + z2 * g,    \
                m3v = nb3 + z3 * g, m4v = nb4 + z4 * g;                        \
    *(f32x2*)p0 = m0v; *(f32x2*)p1 = m1v; *(f32x2*)p2 = m2v;                   \
    *(f32x2*)p3 = m3v; *(f32x2*)p4 = m4v;                                      \
    /* prep next walk candidate (reads after scatter; row base+3 untouched) */ \
    baseW = (base + 1) & 255;                                                  \
    ptrW  = ptr + 1.0f; if (ptrW >= 256.0f) ptrW -= 256.0f;                    \
    wnb0 = m1v; wnb1 = m2v; wnb2 = m3v; wnb3 = m4v;                            \
    wp0 = p1; wp1 = p2; wp2 = p3; wp3 = p4;                                    \
    wp4 = mem + (((base + 3) & 255) << 7) + 2 * l;                             \
    wnb4 = *(f32x2*)wp4;                                                       \
    jtW_pre = jd[baseW];                                                       \
    jt_cur  = jt_nxt;                                                          \
    /* reductions + LN + gate */                                               \
    float s1 = su[0] + su[1];                                                  \
    const f32x2 sq = su * su;  float s2 = sq[0] + sq[1];                       \
    const f32x2 sg = su * wg;  float s3 = sg[0] + sg[1];                       \
    wave_sum64_x3(s1, s2, s3);                                                 \
    const float mu   = s1 * (1.0f / En);                                       \
    const float var  = s2 * (1.0f / En) - mu * mu;                             \
    const float rstd = __builtin_amdgcn_rsqf(var + LN_EPS);                    \
    hid = (su - mu) * rstd * lnw + lnb;                                        \
    jl  = s3 + bgs;                                                            \
}

    // rotating stage-buffer indices: cb = chunk k's buffer, nbf = chunk k+1's
    int cb = 0, nbf = 1;
    for (int k = 0; k < 64; ++k) {
        #pragma unroll
        for (int g = 0; g < 4; ++g) {
            // prefetch next group (group g+1 of chunk k, or group 0 of k+1);
            // target buffer is never producer-active (triple buffering)
            const float* sb;
            if (g < 3) sb = stg + cb  * 2048 + (g + 1) * 512 + 4 * l;
            else       sb = stg + ((k + 1 < 64) ? nbf : cb) * 2048
                              + ((k + 1 < 64) ? 0 : 3) * 512 + 4 * l;
            float4 B0 = *(const float4*)sb;
            float4 B1 = *(const float4*)(sb + 256);
            SSTEP(A0.x, A1.x)
            SSTEP(A0.y, A1.y)
            SSTEP(A0.z, A1.z)
            SSTEP(A0.w, A1.w)
            A0 = B0; A1 = B1;
        }
        cb = nbf; nbf = (nbf == 2) ? 0 : nbf + 1;
        __syncthreads();               // chunk boundary (chunk k+2 staged)
    }
#undef SSTEP

    // epilogue: logits = hid @ Wo^T + bo
    mem[l] = hid[0]; mem[64 + l] = hid[1];
    __syncthreads();                   // final
    const float4* w4 = (const float4*)(Wo + l * En);
    const float4* h4 = (const float4*)mem;
    float a0 = 0.f, a1 = 0.f, a2 = 0.f, a3 = 0.f;
    #pragma unroll
    for (int i = 0; i < En / 4; ++i) {
        float4 wv = w4[i]; float4 hv = h4[i];
        a0 += wv.x * hv.x; a1 += wv.y * hv.y; a2 += wv.z * hv.z; a3 += wv.w * hv.w;
    }
    out[b * NOUTn + l] = (a0 + a1) + (a2 + a3) + bo[l];
}

extern "C" void kernel_launch(void* const* d_in, const int* in_sizes, int n_in,
                              void* d_out, int out_size, void* d_ws, size_t ws_size,
                              hipStream_t stream) {
    const float* x            = (const float*)d_in[0];
    const float* pointer_init = (const float*)d_in[1];
    const float* W_in         = (const float*)d_in[2];
    const float* b_in         = (const float*)d_in[3];
    const float* ln_w         = (const float*)d_in[4];
    const float* ln_b         = (const float*)d_in[5];
    const float* jump_dest    = (const float*)d_in[6];
    const float* Wg           = (const float*)d_in[7];
    const float* bg           = (const float*)d_in[8];
    const float* cs           = (const float*)d_in[9];
    const float* Wo           = (const float*)d_in[10];
    const float* bo           = (const float*)d_in[11];
    float* out = (float*)d_out;
    (void)d_ws; (void)ws_size;   // no workspace needed: emb staged in LDS

    (void)hipFuncSetAttribute((const void*)fused2_kernel,
                              hipFuncAttributeMaxDynamicSharedMemorySize, LDSF_BYTES);
    fused2_kernel<<<Bn, 192, LDSF_BYTES, stream>>>(
        x, pointer_init, W_in, b_in, ln_w, ln_b, jump_dest, Wg, bg, cs,
        Wo, bo, out);
}

// Round 12
// 471.736 us; speedup vs baseline: 1.0339x; 1.0070x over previous
//
#include <hip/hip_runtime.h>
#include <math.h>

// Problem constants (from reference)
#define Bn    256
#define Tn    1024
#define In    64
#define Pn    256
#define En    128
#define NOUTn 64
#define LN_EPS 1e-5f

// softmax factorization constants (TEMP=8):
// z_j ∝ exp((j-2)*frac/4) * exp(-(j-2)^2/8)  (common exp(-frac^2/8) cancels)
#define C1f 0.3606737602222409f     // log2(e)/4
#define K1f 0.8824969025845955f     // exp(-1/8)
#define K2f 0.6065306597126334f     // exp(-4/8)

typedef float f32x2 __attribute__((ext_vector_type(2)));

__device__ __forceinline__ float tanh_fast(float x) {
    float e = __builtin_amdgcn_exp2f(x * 2.88539008177793f);   // e^(2x)
    return 1.0f - 2.0f * __builtin_amdgcn_rcpf(e + 1.0f);
}
__device__ __forceinline__ f32x2 tanh2(f32x2 x) {
    f32x2 e;
    e[0] = __builtin_amdgcn_exp2f(x[0] * 2.88539008177793f);
    e[1] = __builtin_amdgcn_exp2f(x[1] * 2.88539008177793f);
    f32x2 r;
    r[0] = __builtin_amdgcn_rcpf(e[0] + 1.0f);
    r[1] = __builtin_amdgcn_rcpf(e[1] + 1.0f);
    return 1.0f - 2.0f * r;
}

template<int CTRL, int RMASK>
__device__ __forceinline__ float dpp_add(float x) {
    return x + __int_as_float(__builtin_amdgcn_update_dpp(
        0, __float_as_int(x), CTRL, RMASK, 0xF, false));
}
__device__ __forceinline__ void wave_sum64_x3(float& x, float& y, float& z) {
#define LVL(C, R) x = dpp_add<C, R>(x); y = dpp_add<C, R>(y); z = dpp_add<C, R>(z);
    LVL(0x111, 0xF)
    LVL(0x112, 0xF)
    LVL(0x114, 0xF)
    LVL(0x118, 0xF)
    LVL(0x142, 0xA)
    LVL(0x143, 0xC)
#undef LVL
    x = __int_as_float(__builtin_amdgcn_readlane(__float_as_int(x), 63));
    y = __int_as_float(__builtin_amdgcn_readlane(__float_as_int(y), 63));
    z = __int_as_float(__builtin_amdgcn_readlane(__float_as_int(z), 63));
}

// ===========================================================================
// FULLY-FUSED kernel, zero workspace: 256 blocks x 192 threads (3 waves).
//   wave0 (consumer): scan4 step over 64 chunks of 16 timesteps; emb read
//                     from a triple-buffered LDS stage (one ds_read_b128
//                     pair per 4-step group, prefetched one group ahead).
//   waves1-2 (producers): emb chunk k+2 into stage buf[(k+2)%3] while the
//                     consumer scans chunk k from buf[k%3]. Thread tile
//                     4t x 4e; x and W_in loaded with per-lane VMEM dwordx4
//                     (lane-derived tq/eidx -> never scalarized). Per-dot
//                     accumulation order bit-identical to R8's producer.
// Triple buffering makes the consumer's cross-chunk group prefetch race-free:
// during chunk k, producers touch only buf[(k+2)%3]; consumer reads buf[k%3]
// and prefetches at most into buf[(k+1)%3].
// LDS: ring 128 KB + jd 1 KB + stage 3x8 KB = 153 KB (fits 160 KB).
// No global emb traffic at all (R8 paid a 128 MiB HBM round-trip for it).
// ===========================================================================
#define STAGE_FLOATS (3 * 16 * En)                 // 6144
#define LDSF_FLOATS  (Pn * En + Pn + STAGE_FLOATS) // 39168
#define LDSF_BYTES   (LDSF_FLOATS * 4)             // 156672

__global__ __launch_bounds__(192, 1)
void fused2_kernel(const float* __restrict__ x,
                   const float* __restrict__ pointer_init,
                   const float* __restrict__ W_in, const float* __restrict__ b_in,
                   const float* __restrict__ ln_w, const float* __restrict__ ln_b,
                   const float* __restrict__ jump_dest,
                   const float* __restrict__ Wg,  const float* __restrict__ bg,
                   const float* __restrict__ cs_ptr,
                   const float* __restrict__ Wo,  const float* __restrict__ bo,
                   float* __restrict__ out) {
    extern __shared__ float lds[];
    float* mem = lds;                    // ring: [row][2*l + c]
    float* jd  = lds + Pn * En;          // jump_dest copy
    float* stg = lds + Pn * En + Pn;     // stage: [buf3][tq4][e128][t4]

    const int b   = blockIdx.x;
    const int tid = threadIdx.x;

    if (tid >= 64) {
        // ================= PRODUCERS (waves 1,2): 4t x 4e register tile ======
        const int p    = tid - 64;        // 0..127
        const int tq   = p >> 5;          // 0..3 : which 4-t group of the chunk
        const int eidx = p & 31;          // e = eidx + 32*j, j=0..3
        float be[4];
        #pragma unroll
        for (int j = 0; j < 4; ++j) be[j] = b_in[eidx + 32 * j];
        const float* xb = x + (size_t)b * Tn * In;

#define PRODUCE(K, BUF) {                                                     \
    const int t0 = (K) * 16 + tq * 4;                                         \
    const float4* xr = (const float4*)(xb + t0 * In);   /* per-lane addr */   \
    float acc[4][4];                                                          \
    _Pragma("unroll")                                                         \
    for (int tt = 0; tt < 4; ++tt)                                            \
        _Pragma("unroll")                                                     \
        for (int j = 0; j < 4; ++j) acc[tt][j] = 0.f;                         \
    _Pragma("unroll")                                                         \
    for (int i4 = 0; i4 < 16; ++i4) {                                         \
        float4 xv[4];                                                         \
        _Pragma("unroll")                                                     \
        for (int tt = 0; tt < 4; ++tt) xv[tt] = xr[tt * 16 + i4];             \
        float4 wf[4];                                                         \
        _Pragma("unroll")                                                     \
        for (int j = 0; j < 4; ++j)                                           \
            wf[j] = *(const float4*)(W_in + (eidx + 32 * j) * In + i4 * 4);   \
        _Pragma("unroll")                                                     \
        for (int tt = 0; tt < 4; ++tt)                                        \
            _Pragma("unroll")                                                 \
            for (int j = 0; j < 4; ++j) {                                     \
                acc[tt][j] += xv[tt].x * wf[j].x;                             \
                acc[tt][j] += xv[tt].y * wf[j].y;                             \
                acc[tt][j] += xv[tt].z * wf[j].z;                             \
                acc[tt][j] += xv[tt].w * wf[j].w;                             \
            }                                                                 \
    }                                                                         \
    float* sg = stg + (BUF) * 2048 + tq * 512;                                \
    _Pragma("unroll")                                                         \
    for (int j = 0; j < 4; ++j) {                                             \
        float4 o;                                                             \
        o.x = tanh_fast(acc[0][j] + be[j]);                                   \
        o.y = tanh_fast(acc[1][j] + be[j]);                                   \
        o.z = tanh_fast(acc[2][j] + be[j]);                                   \
        o.w = tanh_fast(acc[3][j] + be[j]);                                   \
        *(float4*)(sg + (eidx + 32 * j) * 4) = o;                             \
    }                                                                         \
}
        PRODUCE(0, 0)
        PRODUCE(1, 1)
        __syncthreads();                   // #1: chunks 0,1 staged
        int buf = 2;
        for (int k = 0; k < 64; ++k) {
            if (k + 2 < 64) {
                PRODUCE(k + 2, buf)
                buf = (buf == 2) ? 0 : buf + 1;
            }
            __syncthreads();               // chunk boundary
        }
#undef PRODUCE
        __syncthreads();                   // final: hid broadcast
        return;
    }

    // ================= CONSUMER (wave 0): scan4 step, LDS-staged emb =========
    const int l = tid;

    float4* m4 = (float4*)mem;
    for (int i = l; i < Pn * En / 4; i += 64) m4[i] = make_float4(0.f, 0.f, 0.f, 0.f);
    for (int i = l; i < Pn; i += 64) jd[i] = jump_dest[i];

    const f32x2 lnw = {ln_w[l], ln_w[l + 64]};
    const f32x2 lnb = {ln_b[l], ln_b[l + 64]};
    const f32x2 wg  = {Wg[l],   Wg[l + 64]};
    const float bgs = bg[0];
    const float cs  = 1.0f / (1.0f + expf(-cs_ptr[0]));
    f32x2 hid = {0.f, 0.f};

    float* myb = mem + 2 * l;

    // ---- pipeline state (scan4: forced jump to pointer_init at t=0) ----
    float jl      = 1.0f;
    float jt_cur  = pointer_init[b];
    float ptrW    = 0.f;
    int   baseW   = 0;
    float jtW_pre = 0.f;
    float z0 = 0.f, z1 = 0.f, z2 = 1.f, z3 = 0.f, z4 = 0.f, inv = 1.f;
    f32x2 wnb0 = {0,0}, wnb1 = {0,0}, wnb2 = {0,0}, wnb3 = {0,0}, wnb4 = {0,0};
    float *wp0 = myb, *wp1 = myb, *wp2 = myb, *wp3 = myb, *wp4 = myb;

    __syncthreads();                       // #1: emb chunks 0,1 staged

    // A = current 4-step group registers (group tb=0)
    const float* sa0 = stg + 4 * l;        // buf0, group 0, ch l
    float4 A0 = *(const float4*)sa0;
    float4 A1 = *(const float4*)(sa0 + 256);

#define SSTEP(EC0, EC1) {                                                      \
    float ptr; int base;                                                       \
    f32x2 nb0, nb1, nb2, nb3, nb4;                                             \
    float *p0, *p1, *p2, *p3, *p4;                                             \
    float jt_nxt;                                                              \
    if (__builtin_amdgcn_readfirstlane(__float_as_int(jl)) > 0) {              \
        /* JUMP: full gather + weight recompute */                             \
        ptr  = jt_cur;                                                         \
        base = (int)ptr; base = base > 255 ? 255 : base;                       \
        p0 = mem + (((base + 254) & 255) << 7) + 2 * l;                        \
        p1 = mem + (((base + 255) & 255) << 7) + 2 * l;                        \
        p2 = mem + (base << 7) + 2 * l;                                        \
        p3 = mem + (((base + 1) & 255) << 7) + 2 * l;                          \
        p4 = mem + (((base + 2) & 255) << 7) + 2 * l;                          \
        nb0 = *(f32x2*)p0; nb1 = *(f32x2*)p1; nb2 = *(f32x2*)p2;               \
        nb3 = *(f32x2*)p3; nb4 = *(f32x2*)p4;                                  \
        jt_nxt = jd[base];                                                     \
        const float frac = ptr - (float)base;                                  \
        const float r  = __builtin_amdgcn_exp2f(frac * C1f);                   \
        const float ri = __builtin_amdgcn_exp2f(-frac * C1f);                  \
        z0 = K2f * ri * ri; z1 = K1f * ri; z2 = 1.0f;                          \
        z3 = K1f * r;       z4 = K2f * r * r;                                  \
        inv = __builtin_amdgcn_rcpf(((z0 + z1) + (z2 + z3)) + z4);             \
    } else {                                                                   \
        /* WALK: weights carried, window = scattered regs + prefetched row */  \
        ptr = ptrW; base = baseW;                                              \
        nb0 = wnb0; nb1 = wnb1; nb2 = wnb2; nb3 = wnb3; nb4 = wnb4;            \
        p0 = wp0; p1 = wp1; p2 = wp2; p3 = wp3; p4 = wp4;                      \
        jt_nxt = jtW_pre;                                                      \
    }                                                                          \
    const f32x2 ctx = inv * (((nb0 * z0 + nb1 * z1) + (nb2 * z2 + nb3 * z3))   \
                             + nb4 * z4);                                      \
    f32x2 em; em[0] = (EC0); em[1] = (EC1);                                    \
    const f32x2 su = tanh2(em + cs * ctx + hid);                               \
    const f32x2 g  = su * inv;                                                 \
    const f32x2 m0v = nb0 + z0 * g, m1v = nb1 + z1 * g, m2v = nb2 + z2 * g,    \
                m3v = nb3 + z3 * g, m4v = nb4 + z4 * g;                        \
    *(f32x2*)p0 = m0v; *(f32x2*)p1 = m1v; *(f32x2*)p2 = m2v;                   \
    *(f32x2*)p3 = m3v; *(f32x2*)p4 = m4v;                                      \
    /* prep next walk candidate (reads after scatter; row base+3 untouched) */ \
    baseW = (base + 1) & 255;                                                  \
    ptrW  = ptr + 1.0f; if (ptrW >= 256.0f) ptrW -= 256.0f;                    \
    wnb0 = m1v; wnb1 = m2v; wnb2 = m3v; wnb3 = m4v;                            \
    wp0 = p1; wp1 = p2; wp2 = p3; wp3 = p4;                                    \
    wp4 = mem + (((base + 3) & 255) << 7) + 2 * l;                             \
    wnb4 = *(f32x2*)wp4;                                                       \
    jtW_pre = jd[baseW];                                                       \
    jt_cur  = jt_nxt;                                                          \
    /* reductions + LN + gate */                                               \
    float s1 = su[0] + su[1];                                                  \
    const f32x2 sq = su * su;  float s2 = sq[0] + sq[1];                       \
    const f32x2 sg = su * wg;  float s3 = sg[0] + sg[1];                       \
    wave_sum64_x3(s1, s2, s3);                                                 \
    const float mu   = s1 * (1.0f / En);                                       \
    const float var  = s2 * (1.0f / En) - mu * mu;                             \
    const float rstd = __builtin_amdgcn_rsqf(var + LN_EPS);                    \
    hid = (su - mu) * rstd * lnw + lnb;                                        \
    jl  = s3 + bgs;                                                            \
}

    for (int k = 0; k < 64; ++k) {
        #pragma unroll
        for (int g = 0; g < 4; ++g) {
            const int tb  = k * 4 + g;
            int tbn = tb + 1; if (tbn > 255) tbn = 255;
            // prefetch next group: buf[(tbn>>2)%3] is never producer-active
            const float* sb = stg + ((tbn >> 2) % 3) * 2048 + (tbn & 3) * 512 + 4 * l;
            float4 B0 = *(const float4*)sb;
            float4 B1 = *(const float4*)(sb + 256);
            SSTEP(A0.x, A1.x)
            SSTEP(A0.y, A1.y)
            SSTEP(A0.z, A1.z)
            SSTEP(A0.w, A1.w)
            A0 = B0; A1 = B1;
        }
        __syncthreads();               // chunk boundary (chunk k+2 staged)
    }
#undef SSTEP

    // epilogue: logits = hid @ Wo^T + bo
    mem[l] = hid[0]; mem[64 + l] = hid[1];
    __syncthreads();                   // final
    const float4* w4 = (const float4*)(Wo + l * En);
    const float4* h4 = (const float4*)mem;
    float a0 = 0.f, a1 = 0.f, a2 = 0.f, a3 = 0.f;
    #pragma unroll
    for (int i = 0; i < En / 4; ++i) {
        float4 wv = w4[i]; float4 hv = h4[i];
        a0 += wv.x * hv.x; a1 += wv.y * hv.y; a2 += wv.z * hv.z; a3 += wv.w * hv.w;
    }
    out[b * NOUTn + l] = (a0 + a1) + (a2 + a3) + bo[l];
}

extern "C" void kernel_launch(void* const* d_in, const int* in_sizes, int n_in,
                              void* d_out, int out_size, void* d_ws, size_t ws_size,
                              hipStream_t stream) {
    const float* x            = (const float*)d_in[0];
    const float* pointer_init = (const float*)d_in[1];
    const float* W_in         = (const float*)d_in[2];
    const float* b_in         = (const float*)d_in[3];
    const float* ln_w         = (const float*)d_in[4];
    const float* ln_b         = (const float*)d_in[5];
    const float* jump_dest    = (const float*)d_in[6];
    const float* Wg           = (const float*)d_in[7];
    const float* bg           = (const float*)d_in[8];
    const float* cs           = (const float*)d_in[9];
    const float* Wo           = (const float*)d_in[10];
    const float* bo           = (const float*)d_in[11];
    float* out = (float*)d_out;
    (void)d_ws; (void)ws_size;   // no workspace needed: emb staged in LDS

    (void)hipFuncSetAttribute((const void*)fused2_kernel,
                              hipFuncAttributeMaxDynamicSharedMemorySize, LDSF_BYTES);
    fused2_kernel<<<Bn, 192, LDSF_BYTES, stream>>>(
        x, pointer_init, W_in, b_in, ln_w, ln_b, jump_dest, Wg, bg, cs,
        Wo, bo, out);
}